// Round 1
// baseline (6426.237 us; speedup 1.0000x reference)
//
#include <hip/hip_runtime.h>
#include <math.h>

#define HDIM 128
#define NRR  122            // computed rows/cols in the scan region
#define NSTEP 606           // wavefront steps: 4*121 + 121 + 1

struct SmemMain {
  float W14[4][48][49];     // layers 1-4, row-padded to 49 (bank step 17)
  float W5[24][49];
  float W6[12][25];
  float W7[12];
  float B14[4][48];
  float B5[24];
  float B6[12];
  float B7[4];
  float T0[32][49];         // original t (needed for L4 residual)
  float Ta[32][49];
  float Tb[32][49];
  unsigned hist[256];
};

__global__ __launch_bounds__(1024)
void codec_main_kernel(const float* __restrict__ x,
    const float* __restrict__ W1, const float* __restrict__ b1,
    const float* __restrict__ W2, const float* __restrict__ b2,
    const float* __restrict__ W3, const float* __restrict__ b3,
    const float* __restrict__ W4, const float* __restrict__ b4,
    const float* __restrict__ W5, const float* __restrict__ b5,
    const float* __restrict__ W6, const float* __restrict__ b6,
    const float* __restrict__ W7, const float* __restrict__ b7,
    unsigned* __restrict__ g_hist, float* __restrict__ g_sumsq,
    float* __restrict__ g_dpl)
{
  __shared__ SmemMain S;
  const int tid = threadIdx.x;
  const int plane = blockIdx.x;                       // 24 planes (b*c)
  const float* xp = x + (size_t)plane * (HDIM * HDIM);
  float* dpl = g_dpl + (size_t)plane * (NRR * HDIM);  // delta plane [122][128], abs cols

  // ---- stage weights/biases to LDS, zero hist and delta plane ----
  {
    const float* Ws[4] = {W1, W2, W3, W4};
    #pragma unroll
    for (int L = 0; L < 4; ++L)
      for (int i = tid; i < 48 * 48; i += 1024)
        S.W14[L][i / 48][i % 48] = Ws[L][i];
  }
  for (int i = tid; i < 24 * 48; i += 1024) S.W5[i / 48][i % 48] = W5[i];
  for (int i = tid; i < 12 * 24; i += 1024) S.W6[i / 24][i % 24] = W6[i];
  if (tid < 12) S.W7[tid] = W7[tid];
  if (tid < 48) {
    S.B14[0][tid] = b1[tid]; S.B14[1][tid] = b2[tid];
    S.B14[2][tid] = b3[tid]; S.B14[3][tid] = b4[tid];
  }
  if (tid < 24) S.B5[tid] = b5[tid];
  if (tid < 12) S.B6[tid] = b6[tid];
  if (tid == 0) S.B7[0] = b7[0];
  if (tid < 256) S.hist[tid] = 0u;
  for (int i = tid; i < NRR * HDIM; i += 1024) dpl[i] = 0.f;  // pads must be zero
  __syncthreads();

  const int w = tid >> 6, lane = tid & 63;
  const int ls = lane & 7, ps = lane >> 3;   // 8 outputs x 8 pixels per wave
  float sumsq = 0.f;

  for (int T = 0; T < NSTEP; ++T) {
    const int r_lo = (T > 121) ? ((T - 118) >> 2) : 0;      // ceil((T-121)/4)
    int r_hi = T >> 2; if (r_hi > 121) r_hi = 121;
    const int nact = r_hi - r_lo + 1;                       // <= 31

    // ---- gather t = [x_nb(24), d_nb(24)] for each active pixel ----
    {
      const int f = tid & 63;
      #pragma unroll
      for (int pb = 0; pb < 32; pb += 16) {
        const int p = pb + (tid >> 6);
        if (p < nact && f < 48) {
          const int r = r_lo + p, j = T - 4 * r;   // plane coords; abs = (r+3, j+3)
          float v;
          if (f < 24) {                            // x neighbors
            int row, col;
            if (f < 21) { row = r + f / 7;  col = j + f % 7; }      // rows Y-3..Y-1
            else        { row = r + 3;      col = j + (f - 21); }   // row Y, X-3..X-1
            v = xp[row * HDIM + col];
          } else {                                 // delta neighbors
            const int g = f - 24;
            int row, col;
            if (g < 21) { row = r - 3 + g / 7; col = j + g % 7; }   // prev 3 delta rows
            else        { row = r;             col = j + (g - 21); }// left3
            v = (row >= 0) ? dpl[row * HDIM + col] : 0.f;
          }
          S.T0[p][f] = v;
        }
      }
    }
    __syncthreads();

    // ---- layers 1..4: 48 -> 48, lrelu; L4 adds residual t ----
    {
      float (* const bufs[5])[49] = {S.T0, S.Ta, S.Tb, S.Ta, S.Tb};
      #pragma unroll
      for (int L = 0; L < 4; ++L) {
        float (*tin)[49]  = bufs[L];
        float (*tout)[49] = bufs[L + 1];
        for (int task = w; task < 24; task += 16) {
          const int l = (task % 6) * 8 + ls;
          const int p = (task / 6) * 8 + ps;
          if (p < nact) {
            float a0 = S.B14[L][l], a1 = 0.f;
            #pragma unroll 8
            for (int k = 0; k < 48; k += 2) {
              a0 += S.W14[L][l][k]     * tin[p][k];
              a1 += S.W14[L][l][k + 1] * tin[p][k + 1];
            }
            float z = a0 + a1;
            float o = (z >= 0.f) ? z : 0.01f * z;
            if (L == 3) o += S.T0[p][l];
            tout[p][l] = o;
          }
        }
        __syncthreads();
      }
    }

    // ---- L5: 48 -> 24 (Tb -> Ta) ----
    for (int task = w; task < 12; task += 16) {
      const int l = (task % 3) * 8 + ls;
      const int p = (task / 3) * 8 + ps;
      if (p < nact) {
        float a0 = S.B5[l], a1 = 0.f;
        #pragma unroll 8
        for (int k = 0; k < 48; k += 2) {
          a0 += S.W5[l][k]     * S.Tb[p][k];
          a1 += S.W5[l][k + 1] * S.Tb[p][k + 1];
        }
        float z = a0 + a1;
        S.Ta[p][l] = (z >= 0.f) ? z : 0.01f * z;
      }
    }
    __syncthreads();

    // ---- L6: 24 -> 12 (Ta -> Tb) ----
    for (int task = w; task < 8; task += 16) {
      const int l = (task % 2) * 8 + ls;
      const int p = (task / 2) * 8 + ps;
      if (l < 12 && p < nact) {
        float a0 = S.B6[l], a1 = 0.f;
        #pragma unroll
        for (int k = 0; k < 24; k += 2) {
          a0 += S.W6[l][k]     * S.Ta[p][k];
          a1 += S.W6[l][k + 1] * S.Ta[p][k + 1];
        }
        float z = a0 + a1;
        S.Tb[p][l] = (z >= 0.f) ? z : 0.01f * z;
      }
    }
    __syncthreads();

    // ---- L7: 12 -> 1, clip, delta, store + stats (wave 0) ----
    if (tid < 64 && tid < nact) {
      const int p = tid;
      const int r = r_lo + p, j = T - 4 * r;
      float acc = S.B7[0];
      #pragma unroll
      for (int k = 0; k < 12; ++k) acc += S.W7[k] * S.Tb[p][k];
      const float pred = fminf(1.f, fmaxf(-1.f, acc));
      const float delta = xp[(r + 3) * HDIM + (j + 3)] - pred;
      dpl[r * HDIM + (j + 3)] = delta;
      sumsq += delta * delta;
      if (delta <= 1.0f) {               // delta >= -1 by construction; >1 excluded
        int bin = (int)((delta + 1.0f) * 128.0f);
        bin = bin > 255 ? 255 : (bin < 0 ? 0 : bin);
        atomicAdd(&S.hist[bin], 1u);
      }
    }
    __syncthreads();
  }

  // ---- flush per-block stats ----
  if (tid < 64) {
    float v = sumsq;
    #pragma unroll
    for (int off = 32; off; off >>= 1) v += __shfl_down(v, off);
    if (tid == 0) g_sumsq[plane] = v;
  }
  __syncthreads();
  if (tid < 256 && S.hist[tid]) atomicAdd(&g_hist[tid], S.hist[tid]);
}

__global__ void codec_init_kernel(unsigned* g_hist, float* g_sumsq) {
  const int t = threadIdx.x;
  if (t < 256) g_hist[t] = 0u;
  if (t < 24)  g_sumsq[t] = 0.f;
}

__global__ void codec_final_kernel(const unsigned* __restrict__ g_hist,
                                   const float* __restrict__ g_sumsq,
                                   float* __restrict__ out)
{
  __shared__ float sred[256];
  const int t = threadIdx.x;
  sred[t] = (t < 24) ? g_sumsq[t] : 0.f;
  __syncthreads();
  for (int off = 128; off; off >>= 1) {
    if (t < off) sred[t] += sred[t + off];
    __syncthreads();
  }
  const float loss = sqrtf(sred[0] / 387072.f);   // 8*3*126*128
  __syncthreads();

  // histogram entropy; bottom zero-row adds 2928 zeros -> bin 128
  const unsigned c = g_hist[t] + (t == 128 ? 2928u : 0u);
  float ent = 0.f;
  if (c) {
    const float pr = (float)c / 360144.0f;        // de.size = 24*123*122
    ent = -pr * log2f(pr);
  }
  sred[t] = ent;
  __syncthreads();
  for (int off = 128; off; off >>= 1) {
    if (t < off) sred[t] += sred[t + off];
    __syncthreads();
  }
  if (t == 0) { out[0] = loss; out[1] = sred[0] * 0.125f; }
}

extern "C" void kernel_launch(void* const* d_in, const int* in_sizes, int n_in,
                              void* d_out, int out_size, void* d_ws, size_t ws_size,
                              hipStream_t stream) {
  const float* x  = (const float*)d_in[0];
  const float* W1 = (const float*)d_in[1];  const float* b1 = (const float*)d_in[2];
  const float* W2 = (const float*)d_in[3];  const float* b2 = (const float*)d_in[4];
  const float* W3 = (const float*)d_in[5];  const float* b3 = (const float*)d_in[6];
  const float* W4 = (const float*)d_in[7];  const float* b4 = (const float*)d_in[8];
  const float* W5 = (const float*)d_in[9];  const float* b5 = (const float*)d_in[10];
  const float* W6 = (const float*)d_in[11]; const float* b6 = (const float*)d_in[12];
  const float* W7 = (const float*)d_in[13]; const float* b7 = (const float*)d_in[14];

  unsigned* g_hist = (unsigned*)d_ws;           // 256 u32
  float* g_sumsq = (float*)d_ws + 256;          // 24 f32
  float* g_dpl   = (float*)d_ws + 256 + 32;     // 24 * 122*128 f32 (~1.5 MB)

  codec_init_kernel<<<1, 256, 0, stream>>>(g_hist, g_sumsq);
  codec_main_kernel<<<24, 1024, 0, stream>>>(x, W1, b1, W2, b2, W3, b3, W4, b4,
                                             W5, b5, W6, b6, W7, b7,
                                             g_hist, g_sumsq, g_dpl);
  codec_final_kernel<<<1, 256, 0, stream>>>(g_hist, g_sumsq, (float*)d_out);
}